// Round 1
// baseline (151.464 us; speedup 1.0000x reference)
//
#include <hip/hip_runtime.h>
#include <math.h>
#include <stdint.h>

#define D_   2048
#define BLK  256
#define KSEL 64
#define NBIN 2048

// XLA's f32 tanh: rational approx, plain mul/add (XLA emits no FMA), IEEE div.
__device__ __forceinline__ float tanh_xla(float x) {
    const float kMax = 7.90531110763549805f;
    float xc = fminf(fmaxf(x, -kMax), kMax);
    float x2 = __fmul_rn(xc, xc);
    float p = -2.76076847742355e-16f;
    p = __fadd_rn(__fmul_rn(p, x2), 2.00018790482477e-13f);
    p = __fadd_rn(__fmul_rn(p, x2), -8.60467152213735e-11f);
    p = __fadd_rn(__fmul_rn(p, x2), 5.12229709037114e-08f);
    p = __fadd_rn(__fmul_rn(p, x2), 1.48572235717979e-05f);
    p = __fadd_rn(__fmul_rn(p, x2), 6.37261928875436e-04f);
    p = __fadd_rn(__fmul_rn(p, x2), 4.89352455891786e-03f);
    float num = __fmul_rn(xc, p);
    float q = 1.19825839466702e-06f;
    q = __fadd_rn(__fmul_rn(q, x2), 1.18534705686654e-04f);
    q = __fadd_rn(__fmul_rn(q, x2), 2.26843463243900e-03f);
    q = __fadd_rn(__fmul_rn(q, x2), 4.89352518554385e-03f);
    float r = __fdiv_rn(num, q);
    return (fabsf(x) < 0.0004f) ? x : r;
}

// Exact top-KSEL membership for this thread's 8 values (bit patterns of |z|).
// Returns an 8-bit mask. Uses shared hist + candidate resolution with JAX
// tie-breaking (equal value -> lower channel index wins).
__device__ __forceinline__ uint32_t select_mask(
    const uint32_t u[8], int t,
    uint32_t* sbuf, uint32_t* scidx, uint32_t* sscan,
    int* sB, int* sG, int* sNC)
{
    // zero histogram
    for (int i = t; i < NBIN; i += BLK) sbuf[i] = 0u;
    if (t == 0) *sNC = 0;
    __syncthreads();

    int bin[8];
    #pragma unroll
    for (int j = 0; j < 8; ++j) {
        float av = __uint_as_float(u[j]);                 // |z| >= 0
        float bf = fminf(__fmul_rn(av, 256.0f), 2047.0f); // monotone in av
        bin[j] = (int)bf;
        atomicAdd(&sbuf[bin[j]], 1u);
    }
    __syncthreads();

    // per-thread group sum over its 8 bins
    uint32_t s = 0;
    #pragma unroll
    for (int j = 0; j < 8; ++j) s += sbuf[t * 8 + j];
    sscan[t] = s;
    __syncthreads();
    // inclusive suffix-sum over 256 thread-groups (Hillis-Steele)
    for (int step = 1; step < BLK; step <<= 1) {
        uint32_t v = sscan[t] + ((t + step < BLK) ? sscan[t + step] : 0u);
        __syncthreads();
        sscan[t] = v;
        __syncthreads();
    }
    uint32_t excl = (t < BLK - 1) ? sscan[t + 1] : 0u;  // suffix at bin (t+1)*8

    // find boundary bin B: suffix[B] >= K > suffix[B+1]
    uint32_t run = excl;
    for (int j = 7; j >= 0; --j) {
        uint32_t prev = run;
        run += sbuf[t * 8 + j];
        if (run >= (uint32_t)KSEL && prev < (uint32_t)KSEL) {
            *sB = t * 8 + j;
            *sG = (int)prev;
        }
    }
    __syncthreads();
    const int B = *sB;
    const int G = *sG;
    const uint32_t need = (uint32_t)(KSEL - G);

    // gather boundary-bin candidates (sbuf reused as cand value bits)
    int slot[8];
    #pragma unroll
    for (int j = 0; j < 8; ++j) {
        if (bin[j] == B) {
            int sl = atomicAdd(sNC, 1);
            sbuf[sl]  = u[j];
            scidx[sl] = (uint32_t)((j >> 2) * 1024 + t * 4 + (j & 3));
            slot[j] = sl;
        } else slot[j] = -1;
    }
    __syncthreads();
    const int nc = *sNC;

    // exact rank among candidates: (value desc, index asc)
    bool inc[8];
    int cnt = 0;
    for (int i = t; i < nc; i += BLK) {
        uint32_t ui = sbuf[i];
        uint32_t di = scidx[i];
        uint32_t r = 0;
        for (int jj = 0; jj < nc; ++jj) {
            uint32_t uj = sbuf[jj];
            r += (uj > ui || (uj == ui && scidx[jj] < di)) ? 1u : 0u;
        }
        inc[cnt++] = (r < need);
    }
    __syncthreads();
    cnt = 0;
    for (int i = t; i < nc; i += BLK) sbuf[i] = inc[cnt++] ? 1u : 0u;
    __syncthreads();

    uint32_t mask = 0;
    #pragma unroll
    for (int j = 0; j < 8; ++j) {
        bool in = (bin[j] > B) || (slot[j] >= 0 && sbuf[slot[j]] != 0u);
        mask |= (in ? 1u : 0u) << j;
    }
    __syncthreads();  // protect sbuf before any reuse
    return mask;
}

__global__ __launch_bounds__(BLK) void gelu205_kernel(
    const float* __restrict__ x,
    const float* __restrict__ p_log_tau,
    const float* __restrict__ p_log_beta,
    const float* __restrict__ p_log_gamma,
    const float* __restrict__ ema_mean,
    const float* __restrict__ ema_sq,
    const float* __restrict__ ema_out_mean,
    const float* __restrict__ ema_out_sq,
    const float* __restrict__ ema_out_dir,
    float* __restrict__ out)
{
    __shared__ uint32_t sbuf[NBIN];
    __shared__ uint32_t scidx[NBIN];
    __shared__ uint32_t sscan[BLK];
    __shared__ float sred[12];
    __shared__ float sgcos;
    __shared__ int sB, sG, sNC;

    const int t = threadIdx.x;
    const int row = blockIdx.x;
    const float* xr = x + (size_t)row * D_;
    float* outr = out + (size_t)row * D_;

    const float tau   = expf(p_log_tau[0]);
    const float beta  = log1pf(expf(p_log_beta[0]));   // softplus
    const float gamma = log1pf(expf(p_log_gamma[0]));

    float ov[8], ziv[8];
    uint32_t uin[8], uout[8];
    float s_oo = 0.f, s_od = 0.f, s_dd = 0.f;

    #pragma unroll
    for (int g = 0; g < 2; ++g) {
        const int base = g * 1024 + t * 4;
        float4 x4  = *(const float4*)(xr + base);
        float4 m4  = *(const float4*)(ema_mean + base);
        float4 q4  = *(const float4*)(ema_sq + base);
        float4 mo4 = *(const float4*)(ema_out_mean + base);
        float4 qo4 = *(const float4*)(ema_out_sq + base);
        float4 d4  = *(const float4*)(ema_out_dir + base);
        const float* xp  = (const float*)&x4;
        const float* mp  = (const float*)&m4;
        const float* qp  = (const float*)&q4;
        const float* mop = (const float*)&mo4;
        const float* qop = (const float*)&qo4;
        const float* dp  = (const float*)&d4;
        #pragma unroll
        for (int l = 0; l < 4; ++l) {
            const int j = g * 4 + l;
            const float xx = xp[l];
            // gelu, exact reference op order: 0.5*x*(1+tanh(C*(x+0.044715*x*x*x)))
            float a = __fmul_rn(0.044715f, xx);
            a = __fmul_rn(a, xx);
            a = __fmul_rn(a, xx);
            float inner = __fadd_rn(xx, a);
            float tg = tanh_xla(__fmul_rn(0.7978845608028654f, inner));
            float o = __fmul_rn(__fmul_rn(0.5f, xx), __fadd_rn(1.0f, tg));
            ov[j] = o;
            // z_in = (x - mean) / (sqrt(max(sq - mean^2, 1e-4)) + 1e-5)
            float mm  = mp[l];
            float var = fmaxf(__fsub_rn(qp[l], __fmul_rn(mm, mm)), 1e-4f);
            float den = __fadd_rn(__fsqrt_rn(var), 1e-5f);
            float z   = __fdiv_rn(__fsub_rn(xx, mm), den);
            ziv[j] = z;
            uin[j] = __float_as_uint(fabsf(z));
            // z_out
            float mo   = mop[l];
            float varo = fmaxf(__fsub_rn(qop[l], __fmul_rn(mo, mo)), 1e-4f);
            float deno = __fadd_rn(__fsqrt_rn(varo), 1e-5f);
            float zo   = __fdiv_rn(__fsub_rn(o, mo), deno);
            uout[j] = __float_as_uint(fabsf(zo));
            // cosine-gate partial sums
            float dv = dp[l];
            s_oo = fmaf(o, o, s_oo);
            s_od = fmaf(o, dv, s_od);
            s_dd = fmaf(dv, dv, s_dd);
        }
    }

    // block reduction for cosine gate
    #pragma unroll
    for (int off = 32; off > 0; off >>= 1) {
        s_oo += __shfl_xor(s_oo, off);
        s_od += __shfl_xor(s_od, off);
        s_dd += __shfl_xor(s_dd, off);
    }
    const int wid = t >> 6, lane = t & 63;
    if (lane == 0) {
        sred[wid * 3 + 0] = s_oo;
        sred[wid * 3 + 1] = s_od;
        sred[wid * 3 + 2] = s_dd;
    }
    __syncthreads();
    if (t == 0) {
        float oo = sred[0] + sred[3] + sred[6] + sred[9];
        float od = sred[1] + sred[4] + sred[7] + sred[10];
        float dd = sred[2] + sred[5] + sred[8] + sred[11];
        float no = fmaxf(sqrtf(oo), 1e-12f);
        float nd = fmaxf(sqrtf(dd), 1e-12f);
        float cs = od / (no * nd);
        cs = fminf(fmaxf(cs, -1.0f), 1.0f);
        sgcos = expf(-tau * cs);
    }

    // dual exact top-64 (each call begins and ends with __syncthreads)
    uint32_t m_in  = select_mask(uin,  t, sbuf, scidx, sscan, &sB, &sG, &sNC);
    uint32_t m_out = select_mask(uout, t, sbuf, scidx, sscan, &sB, &sG, &sNC);
    const uint32_t inter = m_in & m_out;

    const float gcos = sgcos;
    #pragma unroll
    for (int g = 0; g < 2; ++g) {
        float4 r4;
        float* rp = (float*)&r4;
        #pragma unroll
        for (int l = 0; l < 4; ++l) {
            const int j = g * 4 + l;
            float gv = 1.0f;
            if (inter & (1u << j)) {
                float tg = tanh_xla(__fmul_rn(gamma, ziv[j]));
                gv = __fadd_rn(1.0f, __fmul_rn(beta, tg));
                gv = fminf(fmaxf(gv, 0.1f), 8.0f);
            }
            rp[l] = __fmul_rn(__fmul_rn(ov[j], gv), gcos);
        }
        *(float4*)(outr + g * 1024 + t * 4) = r4;
    }
}

extern "C" void kernel_launch(void* const* d_in, const int* in_sizes, int n_in,
                              void* d_out, int out_size, void* d_ws, size_t ws_size,
                              hipStream_t stream) {
    const float* x             = (const float*)d_in[0];
    // d_in[1] = logit_decay (unused in forward output)
    const float* p_log_tau     = (const float*)d_in[2];
    const float* p_log_beta    = (const float*)d_in[3];
    const float* p_log_gamma   = (const float*)d_in[4];
    const float* ema_mean      = (const float*)d_in[5];
    const float* ema_sq        = (const float*)d_in[6];
    const float* ema_out_mean  = (const float*)d_in[7];
    const float* ema_out_sq    = (const float*)d_in[8];
    const float* ema_out_dir   = (const float*)d_in[9];
    const int rows = in_sizes[0] / D_;

    gelu205_kernel<<<rows, BLK, 0, stream>>>(
        x, p_log_tau, p_log_beta, p_log_gamma,
        ema_mean, ema_sq, ema_out_mean, ema_out_sq, ema_out_dir,
        (float*)d_out);
}

// Round 2
// 108.630 us; speedup vs baseline: 1.3943x; 1.3943x over previous
//
#include <hip/hip_runtime.h>
#include <math.h>
#include <stdint.h>

#define D_    2048
#define BLK   256
#define KSEL  64
#define NBIN  1024   // bin width 1/128 on |z|
#define CAP   128    // max boundary candidates per select

// ---------- exact-path helpers (must match np/XLA rounding) ----------
__device__ __forceinline__ float tanh_xla(float x) {
    const float kMax = 7.90531110763549805f;
    float xc = fminf(fmaxf(x, -kMax), kMax);
    float x2 = __fmul_rn(xc, xc);
    float p = -2.76076847742355e-16f;
    p = __fadd_rn(__fmul_rn(p, x2), 2.00018790482477e-13f);
    p = __fadd_rn(__fmul_rn(p, x2), -8.60467152213735e-11f);
    p = __fadd_rn(__fmul_rn(p, x2), 5.12229709037114e-08f);
    p = __fadd_rn(__fmul_rn(p, x2), 1.48572235717979e-05f);
    p = __fadd_rn(__fmul_rn(p, x2), 6.37261928875436e-04f);
    p = __fadd_rn(__fmul_rn(p, x2), 4.89352455891786e-03f);
    float num = __fmul_rn(xc, p);
    float q = 1.19825839466702e-06f;
    q = __fadd_rn(__fmul_rn(q, x2), 1.18534705686654e-04f);
    q = __fadd_rn(__fmul_rn(q, x2), 2.26843463243900e-03f);
    q = __fadd_rn(__fmul_rn(q, x2), 4.89352518554385e-03f);
    float r = __fdiv_rn(num, q);
    return (fabsf(x) < 0.0004f) ? x : r;
}

__device__ __forceinline__ float gelu_exact(float xx) {
    float a = __fmul_rn(0.044715f, xx);
    a = __fmul_rn(a, xx);
    a = __fmul_rn(a, xx);
    float inner = __fadd_rn(xx, a);
    float tg = tanh_xla(__fmul_rn(0.7978845608028654f, inner));
    return __fmul_rn(__fmul_rn(0.5f, xx), __fadd_rn(1.0f, tg));
}

// ---------- fast-path helpers (loose tolerance) ----------
__device__ __forceinline__ float tanh_fast(float y) {
    float e = __expf(2.0f * y);
    return 1.0f - 2.0f * __builtin_amdgcn_rcpf(1.0f + e);
}

// ---------- pre-kernel: per-channel denominators ----------
__global__ __launch_bounds__(BLK) void prep_kernel(
    const float* __restrict__ m_in, const float* __restrict__ q_in,
    const float* __restrict__ m_out, const float* __restrict__ q_out,
    float* __restrict__ wsp)
{
    int c = blockIdx.x * BLK + threadIdx.x;
    if (c >= D_) return;
    float mi = m_in[c];
    float vi = fmaxf(__fsub_rn(q_in[c], __fmul_rn(mi, mi)), 1e-4f);
    float di = __fadd_rn(__fsqrt_rn(vi), 1e-5f);
    wsp[c]        = di;                       // den_in
    wsp[D_ + c]   = __fdiv_rn(1.0f, di);      // inv_in
    float mo = m_out[c];
    float vo = fmaxf(__fsub_rn(q_out[c], __fmul_rn(mo, mo)), 1e-4f);
    float dd = __fadd_rn(__fsqrt_rn(vo), 1e-5f);
    wsp[2 * D_ + c] = dd;                     // den_out
    wsp[3 * D_ + c] = __fdiv_rn(1.0f, dd);    // inv_out
}

// ---------- main kernel: one block per row ----------
__global__ __launch_bounds__(BLK) void gelu205_kernel(
    const float* __restrict__ x,
    const float* __restrict__ p_log_tau,
    const float* __restrict__ p_log_beta,
    const float* __restrict__ p_log_gamma,
    const float* __restrict__ ema_mean,
    const float* __restrict__ ema_out_mean,
    const float* __restrict__ ema_out_dir,
    const float* __restrict__ wsp,
    float* __restrict__ out)
{
    __shared__ uint32_t hist[2 * NBIN];      // [0..1023]=IN (swizzled), [1024..]=OUT
    __shared__ uint32_t sg[2 * BLK];         // group suffix sums (IN, OUT)
    __shared__ uint32_t cbI[CAP], ciI[CAP], cfI[CAP];
    __shared__ uint32_t cbO[CAP], ciO[CAP], cfO[CAP];
    __shared__ float sred[12];
    __shared__ float sgcos;
    __shared__ int sBi, sGi, sNCi, sBo, sGo, sNCo;

    const int t = threadIdx.x;
    const int row = blockIdx.x;
    const float* xr = x + (size_t)row * D_;
    float* outr = out + (size_t)row * D_;

    const float* den_in  = wsp;
    const float* inv_in  = wsp + D_;
    const float* den_out = wsp + 2 * D_;
    const float* inv_out = wsp + 3 * D_;

    const float tau   = expf(p_log_tau[0]);
    const float beta  = log1pf(expf(p_log_beta[0]));
    const float gamma = log1pf(expf(p_log_gamma[0]));

    float xv[8], ov[8], zif[8];
    int bin_in[8], bin_out[8];
    float s_oo = 0.f, s_od = 0.f, s_dd = 0.f;

    #pragma unroll
    for (int g = 0; g < 2; ++g) {
        const int base = g * 1024 + t * 4;
        float4 x4  = *(const float4*)(xr + base);
        float4 m4  = *(const float4*)(ema_mean + base);
        float4 i4  = *(const float4*)(inv_in + base);
        float4 mo4 = *(const float4*)(ema_out_mean + base);
        float4 io4 = *(const float4*)(inv_out + base);
        float4 d4  = *(const float4*)(ema_out_dir + base);
        const float* xp  = (const float*)&x4;
        const float* mp  = (const float*)&m4;
        const float* ip  = (const float*)&i4;
        const float* mop = (const float*)&mo4;
        const float* iop = (const float*)&io4;
        const float* dp  = (const float*)&d4;
        #pragma unroll
        for (int l = 0; l < 4; ++l) {
            const int j = g * 4 + l;
            const float xx = xp[l];
            xv[j] = xx;
            // fast gelu: x * sigmoid(1.5957691x_inner)
            float x2 = xx * xx;
            float inner = fmaf(0.044715f * xx, x2, xx);
            float e = __expf(-1.5957691216057308f * inner);
            float o = xx * __builtin_amdgcn_rcpf(1.0f + e);
            ov[j] = o;
            // fast z-scores (binning + gate only; boundary resolved exactly)
            float zi = (xx - mp[l]) * ip[l];
            zif[j] = zi;
            bin_in[j] = (int)fminf(fabsf(zi) * 128.0f, 1023.0f);
            float zo = (o - mop[l]) * iop[l];
            bin_out[j] = (int)fminf(fabsf(zo) * 128.0f, 1023.0f);
            // cosine partials
            float dv = dp[l];
            s_oo = fmaf(o, o, s_oo);
            s_od = fmaf(o, dv, s_od);
            s_dd = fmaf(dv, dv, s_dd);
        }
    }

    // wave reduce for cosine gate
    #pragma unroll
    for (int off = 32; off > 0; off >>= 1) {
        s_oo += __shfl_xor(s_oo, off);
        s_od += __shfl_xor(s_od, off);
        s_dd += __shfl_xor(s_dd, off);
    }
    const int wid = t >> 6, lane = t & 63;
    if (lane == 0) {
        sred[wid * 3 + 0] = s_oo;
        sred[wid * 3 + 1] = s_od;
        sred[wid * 3 + 2] = s_dd;
    }

    // zero hists + init counters
    #pragma unroll
    for (int i = 0; i < 8; ++i) hist[t + i * BLK] = 0u;
    if (t == 0) { sNCi = 0; sNCo = 0; }
    __syncthreads();                                   // B1

    // build both histograms (swizzled: bin b -> (b>>2) + ((b&3)<<8))
    #pragma unroll
    for (int j = 0; j < 8; ++j) {
        int bi = bin_in[j];
        atomicAdd(&hist[(bi >> 2) + ((bi & 3) << 8)], 1u);
        int bo = bin_out[j];
        atomicAdd(&hist[NBIN + (bo >> 2) + ((bo & 3) << 8)], 1u);
    }
    if (t == 0) {
        float oo = sred[0] + sred[3] + sred[6] + sred[9];
        float od = sred[1] + sred[4] + sred[7] + sred[10];
        float dd = sred[2] + sred[5] + sred[8] + sred[11];
        float no = fmaxf(sqrtf(oo), 1e-12f);
        float nd = fmaxf(sqrtf(dd), 1e-12f);
        float cs = fminf(fmaxf(od / (no * nd), -1.0f), 1.0f);
        sgcos = expf(-tau * cs);
    }
    __syncthreads();                                   // B2

    // group sums (4 bins per thread), conflict-free reads
    {
        uint32_t gi = hist[t] + hist[t + 256] + hist[t + 512] + hist[t + 768];
        uint32_t go = hist[NBIN + t] + hist[NBIN + t + 256] +
                      hist[NBIN + t + 512] + hist[NBIN + t + 768];
        sg[t] = gi;
        sg[BLK + t] = go;
    }
    __syncthreads();                                   // B3

    // waves 0/1: suffix scan over 256 group sums -> sg[g] = suffix AFTER group g
    if (wid < 2) {
        uint32_t* bp = sg + wid * BLK;
        uint32_t g0 = bp[4 * lane + 0], g1 = bp[4 * lane + 1];
        uint32_t g2 = bp[4 * lane + 2], g3 = bp[4 * lane + 3];
        uint32_t t3 = g3, t2 = g3 + g2, t1 = t2 + g1, qt = t1 + g0;
        uint32_t S = qt;
        #pragma unroll
        for (int d = 1; d < 64; d <<= 1) {
            uint32_t o = __shfl_down(S, d, 64);
            S += (lane + d < 64) ? o : 0u;
        }
        uint32_t after = S - qt;   // suffix of lanes > lane
        bp[4 * lane + 0] = after + t1;
        bp[4 * lane + 1] = after + t2;
        bp[4 * lane + 2] = after + t3;
        bp[4 * lane + 3] = after;
    }
    __syncthreads();                                   // B4

    // boundary bin find (each thread owns bins 4t..4t+3 for both hists)
    {
        uint32_t run = sg[t];
        #pragma unroll
        for (int j = 3; j >= 0; --j) {
            uint32_t prev = run;
            run += hist[t + (j << 8)];
            if (run >= (uint32_t)KSEL && prev < (uint32_t)KSEL) {
                sBi = 4 * t + j; sGi = (int)prev;
            }
        }
        run = sg[BLK + t];
        #pragma unroll
        for (int j = 3; j >= 0; --j) {
            uint32_t prev = run;
            run += hist[NBIN + t + (j << 8)];
            if (run >= (uint32_t)KSEL && prev < (uint32_t)KSEL) {
                sBo = 4 * t + j; sGo = (int)prev;
            }
        }
    }
    __syncthreads();                                   // B5

    const int Bi = sBi, Bo = sBo;
    int slotI[8], slotO[8];

    // gather boundary candidates; owners recompute EXACT values
    #pragma unroll
    for (int j = 0; j < 8; ++j) {
        slotI[j] = -1;
        if (bin_in[j] == Bi) {
            int ch = (j >> 2) * 1024 + t * 4 + (j & 3);
            float ze = fabsf(__fdiv_rn(__fsub_rn(xv[j], ema_mean[ch]), den_in[ch]));
            int sl = atomicAdd(&sNCi, 1);
            if (sl < CAP) {
                cbI[sl] = __float_as_uint(ze);
                ciI[sl] = (uint32_t)ch;
                slotI[j] = sl;
            }
        }
        slotO[j] = -1;
        if (bin_out[j] == Bo) {
            int ch = (j >> 2) * 1024 + t * 4 + (j & 3);
            float oe = gelu_exact(xv[j]);
            float ze = fabsf(__fdiv_rn(__fsub_rn(oe, ema_out_mean[ch]), den_out[ch]));
            int sl = atomicAdd(&sNCo, 1);
            if (sl < CAP) {
                cbO[sl] = __float_as_uint(ze);
                ciO[sl] = (uint32_t)ch;
                slotO[j] = sl;
            }
        }
    }
    __syncthreads();                                   // B6

    // exact rank among candidates (value desc, index asc = jax top_k tie rule)
    {
        const int nci = min(sNCi, CAP), nco = min(sNCo, CAP);
        const uint32_t needI = (uint32_t)(KSEL - sGi);
        const uint32_t needO = (uint32_t)(KSEL - sGo);
        if (t < 128) {
            for (int i = t; i < nci; i += 128) {
                uint32_t ui = cbI[i], di = ciI[i], r = 0;
                for (int jj = 0; jj < nci; ++jj) {
                    uint32_t uj = cbI[jj];
                    r += (uj > ui || (uj == ui && ciI[jj] < di)) ? 1u : 0u;
                }
                cfI[i] = (r < needI) ? 1u : 0u;
            }
        } else {
            for (int i = t - 128; i < nco; i += 128) {
                uint32_t ui = cbO[i], di = ciO[i], r = 0;
                for (int jj = 0; jj < nco; ++jj) {
                    uint32_t uj = cbO[jj];
                    r += (uj > ui || (uj == ui && ciO[jj] < di)) ? 1u : 0u;
                }
                cfO[i] = (r < needO) ? 1u : 0u;
            }
        }
    }
    __syncthreads();                                   // B7

    // epilogue: gate + write
    const float gcos = sgcos;
    #pragma unroll
    for (int g = 0; g < 2; ++g) {
        float4 r4;
        float* rp = (float*)&r4;
        #pragma unroll
        for (int l = 0; l < 4; ++l) {
            const int j = g * 4 + l;
            float th = tanh_fast(gamma * zif[j]);
            float gv = fminf(fmaxf(fmaf(beta, th, 1.0f), 0.1f), 8.0f);
            bool selI = (bin_in[j] > Bi) || (slotI[j] >= 0 && cfI[slotI[j]] != 0u);
            bool selO = (bin_out[j] > Bo) || (slotO[j] >= 0 && cfO[slotO[j]] != 0u);
            float gate = (selI && selO) ? gv : 1.0f;
            rp[l] = ov[j] * gate * gcos;
        }
        *(float4*)(outr + g * 1024 + t * 4) = r4;
    }
}

extern "C" void kernel_launch(void* const* d_in, const int* in_sizes, int n_in,
                              void* d_out, int out_size, void* d_ws, size_t ws_size,
                              hipStream_t stream) {
    const float* x            = (const float*)d_in[0];
    const float* p_log_tau    = (const float*)d_in[2];
    const float* p_log_beta   = (const float*)d_in[3];
    const float* p_log_gamma  = (const float*)d_in[4];
    const float* ema_mean     = (const float*)d_in[5];
    const float* ema_sq       = (const float*)d_in[6];
    const float* ema_out_mean = (const float*)d_in[7];
    const float* ema_out_sq   = (const float*)d_in[8];
    const float* ema_out_dir  = (const float*)d_in[9];
    float* wsp = (float*)d_ws;
    const int rows = in_sizes[0] / D_;

    prep_kernel<<<(D_ + BLK - 1) / BLK, BLK, 0, stream>>>(
        ema_mean, ema_sq, ema_out_mean, ema_out_sq, wsp);
    gelu205_kernel<<<rows, BLK, 0, stream>>>(
        x, p_log_tau, p_log_beta, p_log_gamma,
        ema_mean, ema_out_mean, ema_out_dir, wsp,
        (float*)d_out);
}

// Round 3
// 96.327 us; speedup vs baseline: 1.5724x; 1.1277x over previous
//
#include <hip/hip_runtime.h>
#include <math.h>
#include <stdint.h>

#define D_    2048
#define BLK   256
#define KSEL  64
#define NBIN  1024   // bin width 1/128 on |z|
#define CAP   128    // max boundary candidates per select

// ---------- exact-path helpers (must match np/XLA rounding) ----------
__device__ __forceinline__ float tanh_xla(float x) {
    const float kMax = 7.90531110763549805f;
    float xc = fminf(fmaxf(x, -kMax), kMax);
    float x2 = __fmul_rn(xc, xc);
    float p = -2.76076847742355e-16f;
    p = __fadd_rn(__fmul_rn(p, x2), 2.00018790482477e-13f);
    p = __fadd_rn(__fmul_rn(p, x2), -8.60467152213735e-11f);
    p = __fadd_rn(__fmul_rn(p, x2), 5.12229709037114e-08f);
    p = __fadd_rn(__fmul_rn(p, x2), 1.48572235717979e-05f);
    p = __fadd_rn(__fmul_rn(p, x2), 6.37261928875436e-04f);
    p = __fadd_rn(__fmul_rn(p, x2), 4.89352455891786e-03f);
    float num = __fmul_rn(xc, p);
    float q = 1.19825839466702e-06f;
    q = __fadd_rn(__fmul_rn(q, x2), 1.18534705686654e-04f);
    q = __fadd_rn(__fmul_rn(q, x2), 2.26843463243900e-03f);
    q = __fadd_rn(__fmul_rn(q, x2), 4.89352518554385e-03f);
    float r = __fdiv_rn(num, q);
    return (fabsf(x) < 0.0004f) ? x : r;
}

__device__ __forceinline__ float gelu_exact(float xx) {
    float a = __fmul_rn(0.044715f, xx);
    a = __fmul_rn(a, xx);
    a = __fmul_rn(a, xx);
    float inner = __fadd_rn(xx, a);
    float tg = tanh_xla(__fmul_rn(0.7978845608028654f, inner));
    return __fmul_rn(__fmul_rn(0.5f, xx), __fadd_rn(1.0f, tg));
}

// ---------- fast-path helpers (loose tolerance) ----------
__device__ __forceinline__ float tanh_fast(float y) {
    float e = __expf(2.0f * y);
    return 1.0f - 2.0f * __builtin_amdgcn_rcpf(1.0f + e);
}

// ---------- pre-kernel: per-channel denominators + ||dir||^2 ----------
__global__ __launch_bounds__(BLK) void prep_kernel(
    const float* __restrict__ m_in, const float* __restrict__ q_in,
    const float* __restrict__ m_out, const float* __restrict__ q_out,
    const float* __restrict__ dirv, float* __restrict__ wsp)
{
    __shared__ float spart[4];
    const int t = threadIdx.x;
    const int c = blockIdx.x * BLK + t;
    if (c < D_) {
        float mi = m_in[c];
        float vi = fmaxf(__fsub_rn(q_in[c], __fmul_rn(mi, mi)), 1e-4f);
        float di = __fadd_rn(__fsqrt_rn(vi), 1e-5f);
        wsp[c]        = di;                       // den_in
        wsp[D_ + c]   = __fdiv_rn(1.0f, di);      // inv_in
        float mo = m_out[c];
        float vo = fmaxf(__fsub_rn(q_out[c], __fmul_rn(mo, mo)), 1e-4f);
        float dd = __fadd_rn(__fsqrt_rn(vo), 1e-5f);
        wsp[2 * D_ + c] = dd;                     // den_out
        wsp[3 * D_ + c] = __fdiv_rn(1.0f, dd);    // inv_out
    }
    if (blockIdx.x == 0) {
        float acc = 0.f;
        #pragma unroll
        for (int k = 0; k < D_ / BLK; ++k) {
            float v = dirv[t + k * BLK];
            acc = fmaf(v, v, acc);
        }
        #pragma unroll
        for (int off = 32; off > 0; off >>= 1) acc += __shfl_xor(acc, off);
        if ((t & 63) == 0) spart[t >> 6] = acc;
        __syncthreads();
        if (t == 0) wsp[4 * D_] = spart[0] + spart[1] + spart[2] + spart[3];
    }
}

// ---------- main kernel: one block per row ----------
__global__ __launch_bounds__(BLK) void gelu205_kernel(
    const float* __restrict__ x,
    const float* __restrict__ p_log_tau,
    const float* __restrict__ p_log_beta,
    const float* __restrict__ p_log_gamma,
    const float* __restrict__ ema_mean,
    const float* __restrict__ ema_out_mean,
    const float* __restrict__ ema_out_dir,
    const float* __restrict__ wsp,
    float* __restrict__ out)
{
    __shared__ uint32_t hist[2 * NBIN];          // [0..1023]=IN, [1024..]=OUT
    __shared__ uint32_t cbI[CAP], ciI[CAP], cfI[CAP];
    __shared__ uint32_t cbO[CAP], ciO[CAP], cfO[CAP];
    __shared__ float sred[8];
    __shared__ float sgcos;
    __shared__ int sBi, sGi, sNCi, sBo, sGo, sNCo;

    const int t = threadIdx.x;
    const int row = blockIdx.x;
    const float* xr = x + (size_t)row * D_;
    float* outr = out + (size_t)row * D_;

    const float* den_in  = wsp;
    const float* inv_in  = wsp + D_;
    const float* den_out = wsp + 2 * D_;
    const float* inv_out = wsp + 3 * D_;
    const float dd_row   = wsp[4 * D_];

    const float tau   = expf(p_log_tau[0]);
    const float beta  = log1pf(expf(p_log_beta[0]));
    const float gamma = log1pf(expf(p_log_gamma[0]));

    float ov[8], zif[8];
    int bin_in[8], bin_out[8];
    float s_oo = 0.f, s_od = 0.f;

    #pragma unroll
    for (int g = 0; g < 2; ++g) {
        const int base = (g << 10) + t * 4;
        float4 x4  = *(const float4*)(xr + base);
        float4 m4  = *(const float4*)(ema_mean + base);
        float4 i4  = *(const float4*)(inv_in + base);
        float4 mo4 = *(const float4*)(ema_out_mean + base);
        float4 io4 = *(const float4*)(inv_out + base);
        float4 d4  = *(const float4*)(ema_out_dir + base);
        const float* xp  = (const float*)&x4;
        const float* mp  = (const float*)&m4;
        const float* ip  = (const float*)&i4;
        const float* mop = (const float*)&mo4;
        const float* iop = (const float*)&io4;
        const float* dp  = (const float*)&d4;
        #pragma unroll
        for (int l = 0; l < 4; ++l) {
            const int j = g * 4 + l;
            const float xx = xp[l];
            // fast gelu: x * sigmoid(1.5957691 * inner)
            float x2 = xx * xx;
            float inner = fmaf(0.044715f * xx, x2, xx);
            float e = __expf(-1.5957691216057308f * inner);
            float o = xx * __builtin_amdgcn_rcpf(1.0f + e);
            ov[j] = o;
            float zi = (xx - mp[l]) * ip[l];
            zif[j] = zi;
            bin_in[j] = (int)fminf(fabsf(zi) * 128.0f, 1023.0f);
            float zo = (o - mop[l]) * iop[l];
            bin_out[j] = (int)fminf(fabsf(zo) * 128.0f, 1023.0f);
            s_oo = fmaf(o, o, s_oo);
            s_od = fmaf(o, dp[l], s_od);
        }
    }

    // wave reduce for cosine gate
    #pragma unroll
    for (int off = 32; off > 0; off >>= 1) {
        s_oo += __shfl_xor(s_oo, off);
        s_od += __shfl_xor(s_od, off);
    }
    const int wid = t >> 6, lane = t & 63;
    if (lane == 0) {
        sred[wid * 2 + 0] = s_oo;
        sred[wid * 2 + 1] = s_od;
    }

    // zero hists (two uint4 stores) + init counters
    {
        uint4 z4 = make_uint4(0u, 0u, 0u, 0u);
        *(uint4*)&hist[t * 8]     = z4;
        *(uint4*)&hist[t * 8 + 4] = z4;
    }
    if (t == 0) { sNCi = 0; sNCo = 0; }
    __syncthreads();                                   // B1

    // build both histograms
    #pragma unroll
    for (int j = 0; j < 8; ++j) {
        atomicAdd(&hist[bin_in[j]], 1u);
        atomicAdd(&hist[NBIN + bin_out[j]], 1u);
    }
    if (t == 0) {
        float oo = sred[0] + sred[2] + sred[4] + sred[6];
        float od = sred[1] + sred[3] + sred[5] + sred[7];
        float no = fmaxf(sqrtf(oo), 1e-12f);
        float nd = fmaxf(sqrtf(dd_row), 1e-12f);
        float cs = fminf(fmaxf(od / (no * nd), -1.0f), 1.0f);
        sgcos = expf(-tau * cs);
    }
    __syncthreads();                                   // B2

    // single-wave suffix scan + boundary find per histogram
    if (wid < 2) {
        const uint32_t* hp = hist + wid * NBIN;
        uint32_t h[16];
        *(uint4*)&h[0]  = *(const uint4*)&hp[lane * 16 + 0];
        *(uint4*)&h[4]  = *(const uint4*)&hp[lane * 16 + 4];
        *(uint4*)&h[8]  = *(const uint4*)&hp[lane * 16 + 8];
        *(uint4*)&h[12] = *(const uint4*)&hp[lane * 16 + 12];
        uint32_t tot = 0;
        #pragma unroll
        for (int k = 0; k < 16; ++k) tot += h[k];
        uint32_t S = tot;
        #pragma unroll
        for (int d2 = 1; d2 < 64; d2 <<= 1) {
            uint32_t o = __shfl_down(S, d2, 64);
            S += (lane + d2 < 64) ? o : 0u;
        }
        uint32_t run = S - tot;   // suffix strictly after this lane's bins
        #pragma unroll
        for (int k = 15; k >= 0; --k) {
            uint32_t prev = run;
            run += h[k];
            if (run >= (uint32_t)KSEL && prev < (uint32_t)KSEL) {
                if (wid == 0) { sBi = lane * 16 + k; sGi = (int)prev; }
                else          { sBo = lane * 16 + k; sGo = (int)prev; }
            }
        }
    }
    __syncthreads();                                   // B3

    const int Bi = sBi, Bo = sBo;
    int slotI[8], slotO[8];

    // gather boundary candidates; owners recompute EXACT values
    #pragma unroll
    for (int j = 0; j < 8; ++j) {
        slotI[j] = -1;
        slotO[j] = -1;
        const int ch = ((j >> 2) << 10) + t * 4 + (j & 3);
        if (bin_in[j] == Bi) {
            float xx = xr[ch];
            float ze = fabsf(__fdiv_rn(__fsub_rn(xx, ema_mean[ch]), den_in[ch]));
            int sl = atomicAdd(&sNCi, 1);
            if (sl < CAP) {
                cbI[sl] = __float_as_uint(ze);
                ciI[sl] = (uint32_t)ch;
                slotI[j] = sl;
            }
        }
        if (bin_out[j] == Bo) {
            float xx = xr[ch];
            float oe = gelu_exact(xx);
            float ze = fabsf(__fdiv_rn(__fsub_rn(oe, ema_out_mean[ch]), den_out[ch]));
            int sl = atomicAdd(&sNCo, 1);
            if (sl < CAP) {
                cbO[sl] = __float_as_uint(ze);
                ciO[sl] = (uint32_t)ch;
                slotO[j] = sl;
            }
        }
    }
    __syncthreads();                                   // B4

    // exact rank among candidates (value desc, index asc = jax tie rule)
    {
        const int nci = min(sNCi, CAP), nco = min(sNCo, CAP);
        const uint32_t needI = (uint32_t)(KSEL - sGi);
        const uint32_t needO = (uint32_t)(KSEL - sGo);
        if (t < 128) {
            for (int i = t; i < nci; i += 128) {
                uint32_t ui = cbI[i], di = ciI[i], r = 0;
                for (int jj = 0; jj < nci; ++jj) {
                    uint32_t uj = cbI[jj];
                    r += (uj > ui || (uj == ui && ciI[jj] < di)) ? 1u : 0u;
                }
                cfI[i] = (r < needI) ? 1u : 0u;
            }
        } else {
            for (int i = t - 128; i < nco; i += 128) {
                uint32_t ui = cbO[i], di = ciO[i], r = 0;
                for (int jj = 0; jj < nco; ++jj) {
                    uint32_t uj = cbO[jj];
                    r += (uj > ui || (uj == ui && ciO[jj] < di)) ? 1u : 0u;
                }
                cfO[i] = (r < needO) ? 1u : 0u;
            }
        }
    }
    __syncthreads();                                   // B5

    // epilogue: lazy gate (tanh only where selected) + write
    const float gcos = sgcos;
    #pragma unroll
    for (int g = 0; g < 2; ++g) {
        float4 r4;
        float* rp = (float*)&r4;
        #pragma unroll
        for (int l = 0; l < 4; ++l) {
            const int j = g * 4 + l;
            bool selI = (bin_in[j] > Bi) || (slotI[j] >= 0 && cfI[slotI[j]] != 0u);
            bool selO = (bin_out[j] > Bo) || (slotO[j] >= 0 && cfO[slotO[j]] != 0u);
            float gate = 1.0f;
            if (selI && selO) {
                float th = tanh_fast(gamma * zif[j]);
                gate = fminf(fmaxf(fmaf(beta, th, 1.0f), 0.1f), 8.0f);
            }
            rp[l] = ov[j] * gate * gcos;
        }
        *(float4*)(outr + (g << 10) + t * 4) = r4;
    }
}

extern "C" void kernel_launch(void* const* d_in, const int* in_sizes, int n_in,
                              void* d_out, int out_size, void* d_ws, size_t ws_size,
                              hipStream_t stream) {
    const float* x            = (const float*)d_in[0];
    const float* p_log_tau    = (const float*)d_in[2];
    const float* p_log_beta   = (const float*)d_in[3];
    const float* p_log_gamma  = (const float*)d_in[4];
    const float* ema_mean     = (const float*)d_in[5];
    const float* ema_sq       = (const float*)d_in[6];
    const float* ema_out_mean = (const float*)d_in[7];
    const float* ema_out_sq   = (const float*)d_in[8];
    const float* ema_out_dir  = (const float*)d_in[9];
    float* wsp = (float*)d_ws;
    const int rows = in_sizes[0] / D_;

    prep_kernel<<<(D_ + BLK - 1) / BLK, BLK, 0, stream>>>(
        ema_mean, ema_sq, ema_out_mean, ema_out_sq, ema_out_dir, wsp);
    gelu205_kernel<<<rows, BLK, 0, stream>>>(
        x, p_log_tau, p_log_beta, p_log_gamma,
        ema_mean, ema_out_mean, ema_out_dir, wsp,
        (float*)d_out);
}

// Round 4
// 76.017 us; speedup vs baseline: 1.9925x; 1.2672x over previous
//
#include <hip/hip_runtime.h>
#include <math.h>
#include <stdint.h>

#define D_    2048
#define BLK   256
#define KSEL  64
#define NBIN  1024   // bin width 1/128 on |z|
#define CAP   128    // max boundary candidates per select

typedef float v2f __attribute__((ext_vector_type(2)));

// ---------- exact-path helpers (must match np/XLA rounding) ----------
__device__ __forceinline__ float tanh_xla(float x) {
    const float kMax = 7.90531110763549805f;
    float xc = fminf(fmaxf(x, -kMax), kMax);
    float x2 = __fmul_rn(xc, xc);
    float p = -2.76076847742355e-16f;
    p = __fadd_rn(__fmul_rn(p, x2), 2.00018790482477e-13f);
    p = __fadd_rn(__fmul_rn(p, x2), -8.60467152213735e-11f);
    p = __fadd_rn(__fmul_rn(p, x2), 5.12229709037114e-08f);
    p = __fadd_rn(__fmul_rn(p, x2), 1.48572235717979e-05f);
    p = __fadd_rn(__fmul_rn(p, x2), 6.37261928875436e-04f);
    p = __fadd_rn(__fmul_rn(p, x2), 4.89352455891786e-03f);
    float num = __fmul_rn(xc, p);
    float q = 1.19825839466702e-06f;
    q = __fadd_rn(__fmul_rn(q, x2), 1.18534705686654e-04f);
    q = __fadd_rn(__fmul_rn(q, x2), 2.26843463243900e-03f);
    q = __fadd_rn(__fmul_rn(q, x2), 4.89352518554385e-03f);
    float r = __fdiv_rn(num, q);
    return (fabsf(x) < 0.0004f) ? x : r;
}

__device__ __forceinline__ float gelu_exact(float xx) {
    float a = __fmul_rn(0.044715f, xx);
    a = __fmul_rn(a, xx);
    a = __fmul_rn(a, xx);
    float inner = __fadd_rn(xx, a);
    float tg = tanh_xla(__fmul_rn(0.7978845608028654f, inner));
    return __fmul_rn(__fmul_rn(0.5f, xx), __fadd_rn(1.0f, tg));
}

// ---------- fast-path helpers (loose tolerance) ----------
__device__ __forceinline__ float tanh_fast(float y) {
    float e = __expf(2.0f * y);
    return 1.0f - 2.0f * __builtin_amdgcn_rcpf(1.0f + e);
}

// ---------- pre-kernel: denominators + ||dir||^2 + scalar params ----------
__global__ __launch_bounds__(BLK) void prep_kernel(
    const float* __restrict__ m_in, const float* __restrict__ q_in,
    const float* __restrict__ m_out, const float* __restrict__ q_out,
    const float* __restrict__ dirv,
    const float* __restrict__ p_log_tau,
    const float* __restrict__ p_log_beta,
    const float* __restrict__ p_log_gamma,
    float* __restrict__ wsp)
{
    __shared__ float spart[4];
    const int t = threadIdx.x;
    const int c = blockIdx.x * BLK + t;
    if (c < D_) {
        float mi = m_in[c];
        float vi = fmaxf(__fsub_rn(q_in[c], __fmul_rn(mi, mi)), 1e-4f);
        float di = __fadd_rn(__fsqrt_rn(vi), 1e-5f);
        wsp[c]        = di;                       // den_in
        wsp[D_ + c]   = __fdiv_rn(1.0f, di);      // inv_in
        float mo = m_out[c];
        float vo = fmaxf(__fsub_rn(q_out[c], __fmul_rn(mo, mo)), 1e-4f);
        float dd = __fadd_rn(__fsqrt_rn(vo), 1e-5f);
        wsp[2 * D_ + c] = dd;                     // den_out
        wsp[3 * D_ + c] = __fdiv_rn(1.0f, dd);    // inv_out
    }
    if (blockIdx.x == 0) {
        float acc = 0.f;
        #pragma unroll
        for (int k = 0; k < D_ / BLK; ++k) {
            float v = dirv[t + k * BLK];
            acc = fmaf(v, v, acc);
        }
        #pragma unroll
        for (int off = 32; off > 0; off >>= 1) acc += __shfl_xor(acc, off);
        if ((t & 63) == 0) spart[t >> 6] = acc;
        __syncthreads();
        if (t == 0) {
            wsp[4 * D_ + 0] = spart[0] + spart[1] + spart[2] + spart[3]; // ||dir||^2
            wsp[4 * D_ + 1] = expf(p_log_tau[0]);                        // tau
            wsp[4 * D_ + 2] = log1pf(expf(p_log_beta[0]));               // beta
            wsp[4 * D_ + 3] = log1pf(expf(p_log_gamma[0]));              // gamma
        }
    }
}

// ---------- main kernel: one block per row ----------
__global__ __launch_bounds__(BLK) void gelu205_kernel(
    const float* __restrict__ x,
    const float* __restrict__ ema_mean,
    const float* __restrict__ ema_out_mean,
    const float* __restrict__ ema_out_dir,
    const float* __restrict__ wsp,
    float* __restrict__ out)
{
    __shared__ uint32_t hist[2 * NBIN];          // [0..1023]=IN, [1024..]=OUT
    __shared__ uint32_t cbI[CAP], ciI[CAP], cfI[CAP];
    __shared__ uint32_t cbO[CAP], ciO[CAP], cfO[CAP];
    __shared__ float sred[8];
    __shared__ float sgcos;
    __shared__ int sBi, sGi, sNCi, sBo, sGo, sNCo;

    const int t = threadIdx.x;
    const int row = blockIdx.x;
    const float* xr = x + (size_t)row * D_;
    float* outr = out + (size_t)row * D_;

    const float* den_in  = wsp;
    const float* inv_in  = wsp + D_;
    const float* den_out = wsp + 2 * D_;
    const float* inv_out = wsp + 3 * D_;
    const float dd_row = wsp[4 * D_ + 0];
    const float tau    = wsp[4 * D_ + 1];
    const float beta   = wsp[4 * D_ + 2];
    const float gamma  = wsp[4 * D_ + 3];

    float ov[8], zif[8];
    int bin_in[8], bin_out[8];
    v2f acc_oo = {0.f, 0.f}, acc_od = {0.f, 0.f};

    #pragma unroll
    for (int g = 0; g < 2; ++g) {
        const int base = (g << 10) + t * 4;
        float4 x4  = *(const float4*)(xr + base);
        float4 m4  = *(const float4*)(ema_mean + base);
        float4 i4  = *(const float4*)(inv_in + base);
        float4 mo4 = *(const float4*)(ema_out_mean + base);
        float4 io4 = *(const float4*)(inv_out + base);
        float4 d4  = *(const float4*)(ema_out_dir + base);
        const v2f* xp2  = (const v2f*)&x4;
        const v2f* mp2  = (const v2f*)&m4;
        const v2f* ip2  = (const v2f*)&i4;
        const v2f* mop2 = (const v2f*)&mo4;
        const v2f* iop2 = (const v2f*)&io4;
        const v2f* dp2  = (const v2f*)&d4;
        #pragma unroll
        for (int p = 0; p < 2; ++p) {
            const int j = g * 4 + p * 2;
            v2f xx = xp2[p];
            // fast gelu (packed): x * sigmoid(1.5957691 * (x + 0.044715 x^3))
            v2f x2 = xx * xx;
            v2f ax = xx * 0.044715f;
            v2f inner = __builtin_elementwise_fma(ax, x2, xx);
            v2f ea = inner * -1.5957691216057308f;
            v2f ev; ev.x = __expf(ea.x); ev.y = __expf(ea.y);
            v2f dn = ev + 1.0f;
            v2f sgm; sgm.x = __builtin_amdgcn_rcpf(dn.x);
            sgm.y = __builtin_amdgcn_rcpf(dn.y);
            v2f o2 = xx * sgm;
            ov[j] = o2.x; ov[j + 1] = o2.y;
            // z-scores (packed), bins (scalar: abs-mod mul, min, cvt)
            v2f zi2 = (xx - mp2[p]) * ip2[p];
            zif[j] = zi2.x; zif[j + 1] = zi2.y;
            bin_in[j]     = (int)fminf(fabsf(zi2.x) * 128.0f, 1023.0f);
            bin_in[j + 1] = (int)fminf(fabsf(zi2.y) * 128.0f, 1023.0f);
            v2f zo2 = (o2 - mop2[p]) * iop2[p];
            bin_out[j]     = (int)fminf(fabsf(zo2.x) * 128.0f, 1023.0f);
            bin_out[j + 1] = (int)fminf(fabsf(zo2.y) * 128.0f, 1023.0f);
            // cosine partials (packed)
            acc_oo = __builtin_elementwise_fma(o2, o2, acc_oo);
            acc_od = __builtin_elementwise_fma(o2, dp2[p], acc_od);
        }
    }
    float s_oo = acc_oo.x + acc_oo.y;
    float s_od = acc_od.x + acc_od.y;

    // wave reduce for cosine gate
    #pragma unroll
    for (int off = 32; off > 0; off >>= 1) {
        s_oo += __shfl_xor(s_oo, off);
        s_od += __shfl_xor(s_od, off);
    }
    const int wid = t >> 6, lane = t & 63;
    if (lane == 0) {
        sred[wid * 2 + 0] = s_oo;
        sred[wid * 2 + 1] = s_od;
    }

    // zero hists + init counters
    {
        uint4 z4 = make_uint4(0u, 0u, 0u, 0u);
        *(uint4*)&hist[t * 8]     = z4;
        *(uint4*)&hist[t * 8 + 4] = z4;
    }
    if (t == 0) { sNCi = 0; sNCo = 0; }
    __syncthreads();                                   // B1

    // build both histograms
    #pragma unroll
    for (int j = 0; j < 8; ++j) {
        atomicAdd(&hist[bin_in[j]], 1u);
        atomicAdd(&hist[NBIN + bin_out[j]], 1u);
    }
    if (t == 0) {
        float oo = sred[0] + sred[2] + sred[4] + sred[6];
        float od = sred[1] + sred[3] + sred[5] + sred[7];
        float no = fmaxf(sqrtf(oo), 1e-12f);
        float nd = fmaxf(sqrtf(dd_row), 1e-12f);
        float cs = fminf(fmaxf(od / (no * nd), -1.0f), 1.0f);
        sgcos = expf(-tau * cs);
    }
    __syncthreads();                                   // B2

    // single-wave suffix scan + boundary find per histogram
    if (wid < 2) {
        const uint32_t* hp = hist + wid * NBIN;
        uint32_t h[16];
        *(uint4*)&h[0]  = *(const uint4*)&hp[lane * 16 + 0];
        *(uint4*)&h[4]  = *(const uint4*)&hp[lane * 16 + 4];
        *(uint4*)&h[8]  = *(const uint4*)&hp[lane * 16 + 8];
        *(uint4*)&h[12] = *(const uint4*)&hp[lane * 16 + 12];
        uint32_t tot = 0;
        #pragma unroll
        for (int k = 0; k < 16; ++k) tot += h[k];
        uint32_t S = tot;
        #pragma unroll
        for (int d2 = 1; d2 < 64; d2 <<= 1) {
            uint32_t o = __shfl_down(S, d2, 64);
            S += (lane + d2 < 64) ? o : 0u;
        }
        uint32_t run = S - tot;   // suffix strictly after this lane's bins
        #pragma unroll
        for (int k = 15; k >= 0; --k) {
            uint32_t prev = run;
            run += h[k];
            if (run >= (uint32_t)KSEL && prev < (uint32_t)KSEL) {
                if (wid == 0) { sBi = lane * 16 + k; sGi = (int)prev; }
                else          { sBo = lane * 16 + k; sGo = (int)prev; }
            }
        }
    }
    __syncthreads();                                   // B3

    const int Bi = sBi, Bo = sBo;
    int slotI[8], slotO[8];

    // gather boundary candidates; owners recompute EXACT values
    #pragma unroll
    for (int j = 0; j < 8; ++j) {
        slotI[j] = -1;
        slotO[j] = -1;
        const int ch = ((j >> 2) << 10) + t * 4 + (j & 3);
        if (bin_in[j] == Bi) {
            float xx = xr[ch];
            float ze = fabsf(__fdiv_rn(__fsub_rn(xx, ema_mean[ch]), den_in[ch]));
            int sl = atomicAdd(&sNCi, 1);
            if (sl < CAP) {
                cbI[sl] = __float_as_uint(ze);
                ciI[sl] = (uint32_t)ch;
                slotI[j] = sl;
            }
        }
        if (bin_out[j] == Bo) {
            float xx = xr[ch];
            float oe = gelu_exact(xx);
            float ze = fabsf(__fdiv_rn(__fsub_rn(oe, ema_out_mean[ch]), den_out[ch]));
            int sl = atomicAdd(&sNCo, 1);
            if (sl < CAP) {
                cbO[sl] = __float_as_uint(ze);
                ciO[sl] = (uint32_t)ch;
                slotO[j] = sl;
            }
        }
    }
    __syncthreads();                                   // B4

    // exact rank among candidates (value desc, index asc = jax tie rule)
    {
        const int nci = min(sNCi, CAP), nco = min(sNCo, CAP);
        const uint32_t needI = (uint32_t)(KSEL - sGi);
        const uint32_t needO = (uint32_t)(KSEL - sGo);
        if (t < 128) {
            for (int i = t; i < nci; i += 128) {
                uint32_t ui = cbI[i], di = ciI[i], r = 0;
                for (int jj = 0; jj < nci; ++jj) {
                    uint32_t uj = cbI[jj];
                    r += (uj > ui || (uj == ui && ciI[jj] < di)) ? 1u : 0u;
                }
                cfI[i] = (r < needI) ? 1u : 0u;
            }
        } else {
            for (int i = t - 128; i < nco; i += 128) {
                uint32_t ui = cbO[i], di = ciO[i], r = 0;
                for (int jj = 0; jj < nco; ++jj) {
                    uint32_t uj = cbO[jj];
                    r += (uj > ui || (uj == ui && ciO[jj] < di)) ? 1u : 0u;
                }
                cfO[i] = (r < needO) ? 1u : 0u;
            }
        }
    }
    __syncthreads();                                   // B5

    // epilogue: lazy gate (tanh only where selected) + write
    const float gcos = sgcos;
    #pragma unroll
    for (int g = 0; g < 2; ++g) {
        float4 r4;
        float* rp = (float*)&r4;
        #pragma unroll
        for (int l = 0; l < 4; ++l) {
            const int j = g * 4 + l;
            bool selI = (bin_in[j] > Bi) || (slotI[j] >= 0 && cfI[slotI[j]] != 0u);
            bool selO = (bin_out[j] > Bo) || (slotO[j] >= 0 && cfO[slotO[j]] != 0u);
            float gate = 1.0f;
            if (selI && selO) {
                float th = tanh_fast(gamma * zif[j]);
                gate = fminf(fmaxf(fmaf(beta, th, 1.0f), 0.1f), 8.0f);
            }
            rp[l] = ov[j] * gate * gcos;
        }
        *(float4*)(outr + (g << 10) + t * 4) = r4;
    }
}

extern "C" void kernel_launch(void* const* d_in, const int* in_sizes, int n_in,
                              void* d_out, int out_size, void* d_ws, size_t ws_size,
                              hipStream_t stream) {
    const float* x            = (const float*)d_in[0];
    const float* p_log_tau    = (const float*)d_in[2];
    const float* p_log_beta   = (const float*)d_in[3];
    const float* p_log_gamma  = (const float*)d_in[4];
    const float* ema_mean     = (const float*)d_in[5];
    const float* ema_sq       = (const float*)d_in[6];
    const float* ema_out_mean = (const float*)d_in[7];
    const float* ema_out_sq   = (const float*)d_in[8];
    const float* ema_out_dir  = (const float*)d_in[9];
    float* wsp = (float*)d_ws;
    const int rows = in_sizes[0] / D_;

    prep_kernel<<<(D_ + BLK - 1) / BLK, BLK, 0, stream>>>(
        ema_mean, ema_sq, ema_out_mean, ema_out_sq, ema_out_dir,
        p_log_tau, p_log_beta, p_log_gamma, wsp);
    gelu205_kernel<<<rows, BLK, 0, stream>>>(
        x, ema_mean, ema_out_mean, ema_out_dir, wsp,
        (float*)d_out);
}

// Round 5
// 74.865 us; speedup vs baseline: 2.0232x; 1.0154x over previous
//
#include <hip/hip_runtime.h>
#include <math.h>
#include <stdint.h>

#define D_    2048
#define BLK   256
#define KSEL  64
#define NBIN  512    // bin width 1/64 on |z|
#define B0    96     // gate: only |z| >= 1.5 enters the histogram (w/ fallback)
#define CAP   128    // max boundary candidates per select

typedef float v2f __attribute__((ext_vector_type(2)));

// ---------- exact-path helpers (must match np/XLA rounding) ----------
__device__ __forceinline__ float tanh_xla(float x) {
    const float kMax = 7.90531110763549805f;
    float xc = fminf(fmaxf(x, -kMax), kMax);
    float x2 = __fmul_rn(xc, xc);
    float p = -2.76076847742355e-16f;
    p = __fadd_rn(__fmul_rn(p, x2), 2.00018790482477e-13f);
    p = __fadd_rn(__fmul_rn(p, x2), -8.60467152213735e-11f);
    p = __fadd_rn(__fmul_rn(p, x2), 5.12229709037114e-08f);
    p = __fadd_rn(__fmul_rn(p, x2), 1.48572235717979e-05f);
    p = __fadd_rn(__fmul_rn(p, x2), 6.37261928875436e-04f);
    p = __fadd_rn(__fmul_rn(p, x2), 4.89352455891786e-03f);
    float num = __fmul_rn(xc, p);
    float q = 1.19825839466702e-06f;
    q = __fadd_rn(__fmul_rn(q, x2), 1.18534705686654e-04f);
    q = __fadd_rn(__fmul_rn(q, x2), 2.26843463243900e-03f);
    q = __fadd_rn(__fmul_rn(q, x2), 4.89352518554385e-03f);
    float r = __fdiv_rn(num, q);
    return (fabsf(x) < 0.0004f) ? x : r;
}

__device__ __forceinline__ float gelu_exact(float xx) {
    float a = __fmul_rn(0.044715f, xx);
    a = __fmul_rn(a, xx);
    a = __fmul_rn(a, xx);
    float inner = __fadd_rn(xx, a);
    float tg = tanh_xla(__fmul_rn(0.7978845608028654f, inner));
    return __fmul_rn(__fmul_rn(0.5f, xx), __fadd_rn(1.0f, tg));
}

// ---------- fast-path helpers (loose tolerance) ----------
__device__ __forceinline__ float tanh_fast(float y) {
    // tanh(y) = 1 - 2/(1+exp(2y));  exp(2y) = exp2(y * 2*log2(e))
    float e = __builtin_amdgcn_exp2f(y * 2.8853900817779268f);
    return 1.0f - 2.0f * __builtin_amdgcn_rcpf(1.0f + e);
}

// ---------- pre-kernel: denominators + ||dir||^2 + scalar params ----------
__global__ __launch_bounds__(BLK) void prep_kernel(
    const float* __restrict__ m_in, const float* __restrict__ q_in,
    const float* __restrict__ m_out, const float* __restrict__ q_out,
    const float* __restrict__ dirv,
    const float* __restrict__ p_log_tau,
    const float* __restrict__ p_log_beta,
    const float* __restrict__ p_log_gamma,
    float* __restrict__ wsp)
{
    __shared__ float spart[4];
    const int t = threadIdx.x;
    const int c = blockIdx.x * BLK + t;
    if (c < D_) {
        float mi = m_in[c];
        float vi = fmaxf(__fsub_rn(q_in[c], __fmul_rn(mi, mi)), 1e-4f);
        float di = __fadd_rn(__fsqrt_rn(vi), 1e-5f);
        wsp[c]        = di;                       // den_in
        wsp[D_ + c]   = __fdiv_rn(1.0f, di);      // inv_in
        float mo = m_out[c];
        float vo = fmaxf(__fsub_rn(q_out[c], __fmul_rn(mo, mo)), 1e-4f);
        float dd = __fadd_rn(__fsqrt_rn(vo), 1e-5f);
        wsp[2 * D_ + c] = dd;                     // den_out
        wsp[3 * D_ + c] = __fdiv_rn(1.0f, dd);    // inv_out
    }
    if (blockIdx.x == 0) {
        float acc = 0.f;
        #pragma unroll
        for (int k = 0; k < D_ / BLK; ++k) {
            float v = dirv[t + k * BLK];
            acc = fmaf(v, v, acc);
        }
        #pragma unroll
        for (int off = 32; off > 0; off >>= 1) acc += __shfl_xor(acc, off);
        if ((t & 63) == 0) spart[t >> 6] = acc;
        __syncthreads();
        if (t == 0) {
            wsp[4 * D_ + 0] = spart[0] + spart[1] + spart[2] + spart[3]; // ||dir||^2
            wsp[4 * D_ + 1] = expf(p_log_tau[0]);                        // tau
            wsp[4 * D_ + 2] = log1pf(expf(p_log_beta[0]));               // beta
            wsp[4 * D_ + 3] = log1pf(expf(p_log_gamma[0]));              // gamma
        }
    }
}

// suffix scan + boundary find over both 512-bin hists (waves 0 and 1)
__device__ __forceinline__ void scan_find(
    const uint32_t* hist, int wid, int lane,
    int* sBi, int* sGi, int* sBo, int* sGo)
{
    if (wid < 2) {
        const uint32_t* hp = hist + wid * NBIN;
        uint32_t h[8];
        *(uint4*)&h[0] = *(const uint4*)&hp[lane * 8 + 0];
        *(uint4*)&h[4] = *(const uint4*)&hp[lane * 8 + 4];
        uint32_t tot = 0;
        #pragma unroll
        for (int k = 0; k < 8; ++k) tot += h[k];
        uint32_t S = tot;
        #pragma unroll
        for (int d2 = 1; d2 < 64; d2 <<= 1) {
            uint32_t o = __shfl_down(S, d2, 64);
            S += (lane + d2 < 64) ? o : 0u;
        }
        uint32_t run = S - tot;   // suffix strictly after this lane's bins
        #pragma unroll
        for (int k = 7; k >= 0; --k) {
            uint32_t prev = run;
            run += h[k];
            if (run >= (uint32_t)KSEL && prev < (uint32_t)KSEL) {
                if (wid == 0) { *sBi = lane * 8 + k; *sGi = (int)prev; }
                else          { *sBo = lane * 8 + k; *sGo = (int)prev; }
            }
        }
    }
}

// ---------- main kernel: one block per row ----------
__global__ __launch_bounds__(BLK) void gelu205_kernel(
    const float* __restrict__ x,
    const float* __restrict__ ema_mean,
    const float* __restrict__ ema_out_mean,
    const float* __restrict__ ema_out_dir,
    const float* __restrict__ wsp,
    float* __restrict__ out)
{
    __shared__ uint32_t hist[2 * NBIN];          // [0..511]=IN, [512..]=OUT
    __shared__ uint32_t cbI[CAP], ciI[CAP], cfI[CAP];
    __shared__ uint32_t cbO[CAP], ciO[CAP], cfO[CAP];
    __shared__ float sred[8];
    __shared__ float sgcos;
    __shared__ int sBi, sGi, sNCi, sBo, sGo, sNCo;

    const int t = threadIdx.x;
    const int row = blockIdx.x;
    const float* xr = x + (size_t)row * D_;
    float* outr = out + (size_t)row * D_;

    const float* den_in  = wsp;
    const float* inv_in  = wsp + D_;
    const float* den_out = wsp + 2 * D_;
    const float* inv_out = wsp + 3 * D_;
    const float dd_row = wsp[4 * D_ + 0];
    const float tau    = wsp[4 * D_ + 1];
    const float beta   = wsp[4 * D_ + 2];
    const float gamma  = wsp[4 * D_ + 3];

    float ov[8], zif[8];
    int bin_in[8], bin_out[8];
    v2f acc_oo = {0.f, 0.f}, acc_od = {0.f, 0.f};

    #pragma unroll
    for (int g = 0; g < 2; ++g) {
        const int base = (g << 10) + t * 4;
        float4 x4  = *(const float4*)(xr + base);
        float4 m4  = *(const float4*)(ema_mean + base);
        float4 i4  = *(const float4*)(inv_in + base);
        float4 mo4 = *(const float4*)(ema_out_mean + base);
        float4 io4 = *(const float4*)(inv_out + base);
        float4 d4  = *(const float4*)(ema_out_dir + base);
        const v2f* xp2  = (const v2f*)&x4;
        const v2f* mp2  = (const v2f*)&m4;
        const v2f* ip2  = (const v2f*)&i4;
        const v2f* mop2 = (const v2f*)&mo4;
        const v2f* iop2 = (const v2f*)&io4;
        const v2f* dp2  = (const v2f*)&d4;
        #pragma unroll
        for (int p = 0; p < 2; ++p) {
            const int j = g * 4 + p * 2;
            v2f xx = xp2[p];
            // fast gelu: x * sigmoid(1.5957691 * (x + 0.044715 x^3))
            // exp(-1.5957691*i) = exp2(i * -1.5957691*log2(e))
            v2f x2 = xx * xx;
            v2f ax = xx * 0.044715f;
            v2f inner = __builtin_elementwise_fma(ax, x2, xx);
            v2f ea = inner * -2.3022269136469443f;
            v2f ev; ev.x = __builtin_amdgcn_exp2f(ea.x);
            ev.y = __builtin_amdgcn_exp2f(ea.y);
            v2f dn = ev + 1.0f;
            v2f sgm; sgm.x = __builtin_amdgcn_rcpf(dn.x);
            sgm.y = __builtin_amdgcn_rcpf(dn.y);
            v2f o2 = xx * sgm;
            ov[j] = o2.x; ov[j + 1] = o2.y;
            v2f zi2 = (xx - mp2[p]) * ip2[p];
            zif[j] = zi2.x; zif[j + 1] = zi2.y;
            bin_in[j]     = (int)fminf(fabsf(zi2.x) * 64.0f, 511.0f);
            bin_in[j + 1] = (int)fminf(fabsf(zi2.y) * 64.0f, 511.0f);
            v2f zo2 = (o2 - mop2[p]) * iop2[p];
            bin_out[j]     = (int)fminf(fabsf(zo2.x) * 64.0f, 511.0f);
            bin_out[j + 1] = (int)fminf(fabsf(zo2.y) * 64.0f, 511.0f);
            acc_oo = __builtin_elementwise_fma(o2, o2, acc_oo);
            acc_od = __builtin_elementwise_fma(o2, dp2[p], acc_od);
        }
    }
    float s_oo = acc_oo.x + acc_oo.y;
    float s_od = acc_od.x + acc_od.y;

    // wave reduce for cosine gate
    #pragma unroll
    for (int off = 32; off > 0; off >>= 1) {
        s_oo += __shfl_xor(s_oo, off);
        s_od += __shfl_xor(s_od, off);
    }
    const int wid = t >> 6, lane = t & 63;
    if (lane == 0) {
        sred[wid * 2 + 0] = s_oo;
        sred[wid * 2 + 1] = s_od;
    }

    // zero hists (one uint4/thread) + init flags
    *(uint4*)&hist[t * 4] = make_uint4(0u, 0u, 0u, 0u);
    if (t == 0) { sNCi = 0; sNCo = 0; sBi = -1; sBo = -1; }
    __syncthreads();                                   // B1

    // gated histogram build: only bins >= B0 can matter (fallback below)
    #pragma unroll
    for (int j = 0; j < 8; ++j) {
        if (bin_in[j] >= B0)  atomicAdd(&hist[bin_in[j]], 1u);
        if (bin_out[j] >= B0) atomicAdd(&hist[NBIN + bin_out[j]], 1u);
    }
    if (t == 0) {
        float oo = sred[0] + sred[2] + sred[4] + sred[6];
        float od = sred[1] + sred[3] + sred[5] + sred[7];
        float no = fmaxf(sqrtf(oo), 1e-12f);
        float nd = fmaxf(sqrtf(dd_row), 1e-12f);
        float cs = fminf(fmaxf(od / (no * nd), -1.0f), 1.0f);
        sgcos = expf(-tau * cs);
    }
    __syncthreads();                                   // B2

    scan_find(hist, wid, lane, &sBi, &sGi, &sBo, &sGo);
    __syncthreads();                                   // B3

    int Bi = sBi, Bo = sBo;
    // uniform fallback: fewer than KSEL elements above the gate -> full hist
    if (Bi < 0 || Bo < 0) {
        #pragma unroll
        for (int j = 0; j < 8; ++j) {
            if (bin_in[j] < B0)  atomicAdd(&hist[bin_in[j]], 1u);
            if (bin_out[j] < B0) atomicAdd(&hist[NBIN + bin_out[j]], 1u);
        }
        __syncthreads();
        scan_find(hist, wid, lane, &sBi, &sGi, &sBo, &sGo);
        __syncthreads();
        Bi = sBi; Bo = sBo;
    }

    int slotI[8], slotO[8];
    // gather boundary candidates; owners recompute EXACT values
    #pragma unroll
    for (int j = 0; j < 8; ++j) {
        slotI[j] = -1;
        slotO[j] = -1;
        const int ch = ((j >> 2) << 10) + t * 4 + (j & 3);
        if (bin_in[j] == Bi) {
            float xx = xr[ch];
            float ze = fabsf(__fdiv_rn(__fsub_rn(xx, ema_mean[ch]), den_in[ch]));
            int sl = atomicAdd(&sNCi, 1);
            if (sl < CAP) {
                cbI[sl] = __float_as_uint(ze);
                ciI[sl] = (uint32_t)ch;
                slotI[j] = sl;
            }
        }
        if (bin_out[j] == Bo) {
            float xx = xr[ch];
            float oe = gelu_exact(xx);
            float ze = fabsf(__fdiv_rn(__fsub_rn(oe, ema_out_mean[ch]), den_out[ch]));
            int sl = atomicAdd(&sNCo, 1);
            if (sl < CAP) {
                cbO[sl] = __float_as_uint(ze);
                ciO[sl] = (uint32_t)ch;
                slotO[j] = sl;
            }
        }
    }
    __syncthreads();                                   // B4

    // exact rank among candidates (value desc, index asc = jax tie rule)
    {
        const int nci = min(sNCi, CAP), nco = min(sNCo, CAP);
        const uint32_t needI = (uint32_t)(KSEL - sGi);
        const uint32_t needO = (uint32_t)(KSEL - sGo);
        if (t < 128) {
            for (int i = t; i < nci; i += 128) {
                uint32_t ui = cbI[i], di = ciI[i], r = 0;
                for (int jj = 0; jj < nci; ++jj) {
                    uint32_t uj = cbI[jj];
                    r += (uj > ui || (uj == ui && ciI[jj] < di)) ? 1u : 0u;
                }
                cfI[i] = (r < needI) ? 1u : 0u;
            }
        } else {
            for (int i = t - 128; i < nco; i += 128) {
                uint32_t ui = cbO[i], di = ciO[i], r = 0;
                for (int jj = 0; jj < nco; ++jj) {
                    uint32_t uj = cbO[jj];
                    r += (uj > ui || (uj == ui && ciO[jj] < di)) ? 1u : 0u;
                }
                cfO[i] = (r < needO) ? 1u : 0u;
            }
        }
    }
    __syncthreads();                                   // B5

    // epilogue: lazy gate (tanh only where selected) + write
    const float gcos = sgcos;
    #pragma unroll
    for (int g = 0; g < 2; ++g) {
        float4 r4;
        float* rp = (float*)&r4;
        #pragma unroll
        for (int l = 0; l < 4; ++l) {
            const int j = g * 4 + l;
            bool selI = (bin_in[j] > Bi) || (slotI[j] >= 0 && cfI[slotI[j]] != 0u);
            bool selO = (bin_out[j] > Bo) || (slotO[j] >= 0 && cfO[slotO[j]] != 0u);
            float gate = 1.0f;
            if (selI && selO) {
                float th = tanh_fast(gamma * zif[j]);
                gate = fminf(fmaxf(fmaf(beta, th, 1.0f), 0.1f), 8.0f);
            }
            rp[l] = ov[j] * gate * gcos;
        }
        *(float4*)(outr + (g << 10) + t * 4) = r4;
    }
}

extern "C" void kernel_launch(void* const* d_in, const int* in_sizes, int n_in,
                              void* d_out, int out_size, void* d_ws, size_t ws_size,
                              hipStream_t stream) {
    const float* x            = (const float*)d_in[0];
    const float* p_log_tau    = (const float*)d_in[2];
    const float* p_log_beta   = (const float*)d_in[3];
    const float* p_log_gamma  = (const float*)d_in[4];
    const float* ema_mean     = (const float*)d_in[5];
    const float* ema_sq       = (const float*)d_in[6];
    const float* ema_out_mean = (const float*)d_in[7];
    const float* ema_out_sq   = (const float*)d_in[8];
    const float* ema_out_dir  = (const float*)d_in[9];
    float* wsp = (float*)d_ws;
    const int rows = in_sizes[0] / D_;

    prep_kernel<<<(D_ + BLK - 1) / BLK, BLK, 0, stream>>>(
        ema_mean, ema_sq, ema_out_mean, ema_out_sq, ema_out_dir,
        p_log_tau, p_log_beta, p_log_gamma, wsp);
    gelu205_kernel<<<rows, BLK, 0, stream>>>(
        x, ema_mean, ema_out_mean, ema_out_dir, wsp,
        (float*)d_out);
}